// Round 25
// baseline (9139.029 us; speedup 1.0000x reference)
//
#include <hip/hip_runtime.h>
#include <stdint.h>

#define B_   4
#define T_   4096
#define D_   1024
#define H_   16
#define M_   16384
#define NTOT 1536
#define BM   128
#define BN   64
#define BKK  16
#define NIT  (D_ / BKK)    // 64
#define KC   384           // OpenBLAS SGEMM_DEFAULT_Q

typedef unsigned short u16;
typedef unsigned long long u64;

__device__ __forceinline__ float bf16r(float f) {
    unsigned int u = __float_as_uint(f);
    u += 0x7FFFu + ((u >> 16) & 1u);
    return __uint_as_float(u & 0xFFFF0000u);
}

// async global->LDS, 16B per lane, dest = wave-uniform base + lane*16
#define GLD16(gsrc, ldst)                                                     \
    __builtin_amdgcn_global_load_lds(                                         \
        (const __attribute__((address_space(1))) void*)(gsrc),                \
        (__attribute__((address_space(3))) void*)(ldst), 16, 0, 0)

// ---------------------------------------------------------------------------
// GEMM on RAW f32 inputs, OpenBLAS order (serial FMA per element within
// KC=384 panels, C += per panel, (P0+P1)+P2). 128x64 block, 8x4/thread.
// Staging via global_load_lds DMA (no VGPR round-trip) into double-buffered
// row-major 16B-slot tiles; DMA for tile it+1 issued before compute(it) so
// HBM/L2 latency hides under 512 FMAs. Slot swizzle S = s ^ ((s>>4)&7)
// (applied on the GLOBAL source per lane) makes A-reads conflict-free and
// B-reads 2-way (free). Per-element accumulation order bit-identical to the
// proven R19/R21 kernels.
// ---------------------------------------------------------------------------
__global__ __launch_bounds__(256, 4) void gemm_pack_kernel(
    const float* __restrict__ x, const float* __restrict__ Wq,
    const float* __restrict__ Wk, const float* __restrict__ Wv,
    u16* __restrict__ qc, u16* __restrict__ kc, u64* __restrict__ vc)
{
    __shared__ float4 Asl[2][512];   // 2 x 128 rows x 4 slots  (16 KB)
    __shared__ float4 Bsl[2][256];   // 2 x  64 rows x 4 slots  ( 8 KB)
    __shared__ unsigned char sb[BM][17];

    const int tid = threadIdx.x;
    const int tx = tid & 15;            // N: cols tx*4..+3
    const int ty = tid >> 4;            // M: rows ty*4+i and 64+ty*4+i
    const int n0 = blockIdx.x * BN;     // x-major: n-tiles share x rows in L2
    const int m0 = blockIdx.y * BM;

    const float* Wsrc; int f0;
    if (n0 < 256)      { Wsrc = Wq; f0 = n0; }
    else if (n0 < 512) { Wsrc = Wk; f0 = n0 - 256; }
    else               { Wsrc = Wv; f0 = n0 - 512; }

    const int wid  = tid >> 6;          // wave 0..3
    const int lane = tid & 63;

    // Per-lane pre-swizzled global sources: linear slot S holds logical slot
    // s = S ^ ((S>>4)&7); s -> (row = s>>2, kc = s&3).
    const float* gA0;
    const float* gA1;
    const float* gB;
    {
        int S0 = wid * 64 + lane;                 // A slots 0..255
        int s0 = S0 ^ ((S0 >> 4) & 7);
        gA0 = x + (size_t)(m0 + (s0 >> 2)) * D_ + (s0 & 3) * 4;
        int S1 = 256 + wid * 64 + lane;           // A slots 256..511
        int s1 = S1 ^ ((S1 >> 4) & 7);
        gA1 = x + (size_t)(m0 + (s1 >> 2)) * D_ + (s1 & 3) * 4;
        int SB = wid * 64 + lane;                 // B slots 0..255
        int sB = SB ^ ((SB >> 4) & 7);
        gB = Wsrc + (size_t)(f0 + (sB >> 2)) * D_ + (sB & 3) * 4;
    }

    float run[8][4], tot[8][4];
    #pragma unroll
    for (int i = 0; i < 8; ++i)
        #pragma unroll
        for (int j = 0; j < 4; ++j) { run[i][j] = 0.f; tot[i][j] = 0.f; }

    // prologue: DMA tile 0 into buffer 0
    GLD16(gA0, &Asl[0][wid * 64]);
    GLD16(gA1, &Asl[0][256 + wid * 64]);
    GLD16(gB,  &Bsl[0][wid * 64]);
    __syncthreads();   // drains vmcnt -> tile 0 resident

    const int mA = ty & 7;   // A-read swizzle mask (== (row>>2)&7 for all 8 rows)
    const int mB = tx & 7;   // B-read swizzle mask

    int buf = 0;
    for (int it = 0; it < NIT; ++it) {
        // issue DMA for tile it+1 into the other buffer (flies under compute)
        if (it + 1 < NIT) {
            const int koff = (it + 1) * BKK;
            GLD16(gA0 + koff, &Asl[buf ^ 1][wid * 64]);
            GLD16(gA1 + koff, &Asl[buf ^ 1][256 + wid * 64]);
            GLD16(gB + koff,  &Bsl[buf ^ 1][wid * 64]);
        }

        const float4* Ab = Asl[buf];
        const float4* Bb = Bsl[buf];

        #pragma unroll
        for (int kc4 = 0; kc4 < 4; ++kc4) {      // 4 k per chunk, ascending
            float4 a[8], b[4];
            #pragma unroll
            for (int i = 0; i < 8; ++i) {
                const int row = (i < 4) ? (ty * 4 + i) : (64 + ty * 4 + (i - 4));
                a[i] = Ab[((row << 2) | kc4) ^ mA];
            }
            #pragma unroll
            for (int j = 0; j < 4; ++j) {
                const int cc = tx * 4 + j;
                b[j] = Bb[((cc << 2) | kc4) ^ mB];
            }
            #pragma unroll
            for (int i = 0; i < 8; ++i)
                #pragma unroll
                for (int j = 0; j < 4; ++j) {
                    run[i][j] = __builtin_fmaf(a[i].x, b[j].x, run[i][j]);
                    run[i][j] = __builtin_fmaf(a[i].y, b[j].y, run[i][j]);
                    run[i][j] = __builtin_fmaf(a[i].z, b[j].z, run[i][j]);
                    run[i][j] = __builtin_fmaf(a[i].w, b[j].w, run[i][j]);
                }
        }

        // OpenBLAS panel boundary after k=384 (it=23) and k=768 (it=47)
        if (it == 23 || it == 47) {
            #pragma unroll
            for (int i = 0; i < 8; ++i)
                #pragma unroll
                for (int j = 0; j < 4; ++j) {
                    tot[i][j] = tot[i][j] + run[i][j];
                    run[i][j] = 0.f;
                }
        }

        __syncthreads();   // all waves done with buf; DMA(it+1) drained
        buf ^= 1;
    }

    // sign-pack: thread -> 8 nibbles (one per row, cols tx*4..+3)
    #pragma unroll
    for (int i = 0; i < 8; ++i) {
        const int r = (i < 4) ? (ty * 4 + i) : (64 + ty * 4 + (i - 4));
        unsigned char nb = 0;
        #pragma unroll
        for (int j = 0; j < 4; ++j) {
            float v = tot[i][j] + run[i][j];   // C = (P0+P1)+P2
            nb |= (unsigned char)((v > 0.0f) ? (1u << j) : 0u);
        }
        sb[r][tx] = nb;
    }
    __syncthreads();

    if (tid < BM) {
        const int r = tid;
        u64 row = 0ULL;
        #pragma unroll
        for (int nb2 = 0; nb2 < 16; ++nb2)
            row |= (u64)(sb[r][nb2] & 0xFu) << (nb2 * 4);
        const int m = m0 + r;
        const int b = m >> 12;
        const int t = m & (T_ - 1);
        if (n0 < 512) {
            u16* dst = (n0 < 256) ? qc : kc;
            const int hb = (n0 & 255) >> 4;
            #pragma unroll
            for (int g = 0; g < 4; ++g)
                dst[((size_t)(b * H_ + hb + g)) * T_ + t] = (u16)((row >> (g * 16)) & 0xFFFFULL);
        } else {
            const int h = (n0 - 512) >> 6;
            vc[((size_t)(b * H_ + h)) * T_ + t] = row;
        }
    }
}

// ---------------------------------------------------------------------------
// Fused resolve + expand (bit-identical to the R19 proven kernel).
// ---------------------------------------------------------------------------
__global__ __launch_bounds__(256) void resolve_expand_kernel(
    const u16* __restrict__ qc, const u16* __restrict__ kc,
    const u64* __restrict__ vc,
    const float* __restrict__ emb0, const float* __restrict__ emb1,
    float* __restrict__ out)
{
    __shared__ u16 keys[T_];
    __shared__ u16 pos[T_];
    __shared__ unsigned int cnt[256];
    __shared__ unsigned int offs[257];
    __shared__ float e_lo[64], e_hi[64];

    const int bh = blockIdx.x;
    const int b = bh >> 4, h = bh & 15;
    const u16* kck = kc + (size_t)bh * T_;
    const u16* qck = qc + (size_t)bh * T_;
    const u64* vck = vc + (size_t)bh * T_;
    const int tid = threadIdx.x;

    if (tid < 64) {
        e_lo[tid] = bf16r(emb0[h * 64 + tid]);
        e_hi[tid] = bf16r(emb1[h * 64 + tid]);
    }
    cnt[tid] = 0;
    __syncthreads();
    for (int t = tid; t < T_; t += 256) {
        u16 kv = kck[t];
        keys[t] = kv;
        atomicAdd(&cnt[kv & 255], 1u);
    }
    __syncthreads();
    if (tid == 0) {
        unsigned int s = 0;
        for (int i = 0; i < 256; ++i) { offs[i] = s; s += cnt[i]; }
        offs[256] = s;
    }
    __syncthreads();
    cnt[tid] = offs[tid];
    __syncthreads();
    for (int t = tid; t < T_; t += 256) {
        unsigned int p = atomicAdd(&cnt[keys[t] & 255], 1u);
        pos[p] = (u16)t;
    }
    __syncthreads();
    for (int t = tid; t < T_; t += 256) {
        u16 code = qck[t];
        const int bkt = code & 255;
        int best = -1;
        const unsigned int s = offs[bkt], e = offs[bkt + 1];
        for (unsigned int it = s; it < e; ++it) {
            int j = (int)pos[it];
            if (j < t && keys[j] == code && j > best) best = j;
        }
        u64 yv = (best >= 0) ? vck[best] : 0ULL;
        float* orow = out + ((size_t)(b * T_ + t)) * D_ + h * 64;
        #pragma unroll
        for (int e2 = 0; e2 < 64; ++e2)
            orow[e2] = ((yv >> e2) & 1ULL) ? e_hi[e2] : e_lo[e2];
    }
}

// ---------------------------------------------------------------------------
extern "C" void kernel_launch(void* const* d_in, const int* in_sizes, int n_in,
                              void* d_out, int out_size, void* d_ws, size_t ws_size,
                              hipStream_t stream)
{
    const float* x  = (const float*)d_in[0];
    const float* Wq = (const float*)d_in[1];
    const float* Wk = (const float*)d_in[2];
    const float* Wv = (const float*)d_in[3];
    const float* e0 = (const float*)d_in[4];
    const float* e1 = (const float*)d_in[5];

    char* ws = (char*)d_ws;
    // footprint 3 MB (safe): qc 512K | kc 512K | vc 2M
    u16* qc = (u16*)(ws + 0);
    u16* kc = (u16*)(ws + 524288);
    u64* vc = (u64*)(ws + 1048576);
    float* out = (float*)d_out;

    dim3 gA(NTOT / BN, M_ / BM);   // (24, 128), x-major shares x-rows in L2
    gemm_pack_kernel<<<gA, 256, 0, stream>>>(x, Wq, Wk, Wv, qc, kc, vc);
    resolve_expand_kernel<<<B_ * H_, 256, 0, stream>>>(qc, kc, vc, e0, e1, out);
}

// Round 26
// 774.653 us; speedup vs baseline: 11.7976x; 11.7976x over previous
//
#include <hip/hip_runtime.h>
#include <stdint.h>

#define B_   4
#define T_   4096
#define D_   1024
#define H_   16
#define M_   16384
#define NTOT 1536
#define BM   128
#define BN   64
#define BKK  32
#define NIT  (D_ / BKK)    // 32
#define KC   384           // OpenBLAS SGEMM_DEFAULT_Q

typedef unsigned short u16;
typedef unsigned long long u64;

__device__ __forceinline__ float bf16r(float f) {
    unsigned int u = __float_as_uint(f);
    u += 0x7FFFu + ((u >> 16) & 1u);
    return __uint_as_float(u & 0xFFFF0000u);
}

// ---------------------------------------------------------------------------
// GEMM on RAW f32 inputs, OpenBLAS order (serial FMA per element within
// KC=384 panels, C += per panel, (P0+P1)+P2). 128x64 block, 8x4/thread.
// BKK=32 staged per iteration (halved barrier count vs the 750us R21), but
// computed as TWO sequential 16-k phases -- each phase is exactly R21's
// known-good inner loop, and the outer phase loop is #pragma unroll 1 so
// the compiler cannot fuse them into R24's VGPR-exploding 32-deep unroll.
// __launch_bounds__(256,6) hard-caps VGPR (~85) as insurance.
// Per-element accumulation order bit-identical to the proven R19/R21 kernels.
// ---------------------------------------------------------------------------
__global__ __launch_bounds__(256, 6) void gemm_pack_kernel(
    const float* __restrict__ x, const float* __restrict__ Wq,
    const float* __restrict__ Wk, const float* __restrict__ Wv,
    u16* __restrict__ qc, u16* __restrict__ kc, u64* __restrict__ vc)
{
    __shared__ float As[BKK][BM + 4];   // [32][132] = 16.9 KB
    __shared__ float Bs[BKK][BN + 4];   // [32][68]  =  8.7 KB
    __shared__ unsigned char sb[BM][17];

    const int tid = threadIdx.x;
    const int tx = tid & 15;            // N: cols tx*4..+3
    const int ty = tid >> 4;            // M: rows ty*4+i and 64+ty*4+i
    const int n0 = blockIdx.x * BN;     // x-major: n-tiles share x rows in L2
    const int m0 = blockIdx.y * BM;

    const float* Wsrc; int f0;
    if (n0 < 256)      { Wsrc = Wq; f0 = n0; }
    else if (n0 < 512) { Wsrc = Wk; f0 = n0 - 256; }
    else               { Wsrc = Wv; f0 = n0 - 512; }

    // staging indices: 8 float4-groups across 32 k, rows step 32
    const int sm  = tid >> 3;           // 0..31
    const int skg = tid & 7;            // k-group 0..7

    float run[8][4], tot[8][4];
    #pragma unroll
    for (int i = 0; i < 8; ++i)
        #pragma unroll
        for (int j = 0; j < 4; ++j) { run[i][j] = 0.f; tot[i][j] = 0.f; }

    for (int it = 0; it < NIT; ++it) {
        const int k0 = it * BKK;
        __syncthreads();   // previous compute done -> LDS safe to overwrite

        // stage x: 128 rows x 8 k-groups (4 per thread), written immediately
        #pragma unroll
        for (int l = 0; l < 4; ++l) {
            const int m = sm + l * 32;
            float4 v = *(const float4*)&x[(size_t)(m0 + m) * D_ + k0 + skg * 4];
            As[skg * 4 + 0][m] = v.x; As[skg * 4 + 1][m] = v.y;
            As[skg * 4 + 2][m] = v.z; As[skg * 4 + 3][m] = v.w;
        }
        // stage W: 64 rows x 8 k-groups (2 per thread)
        #pragma unroll
        for (int l = 0; l < 2; ++l) {
            const int n = sm + l * 32;
            float4 v = *(const float4*)&Wsrc[(size_t)(f0 + n) * D_ + k0 + skg * 4];
            Bs[skg * 4 + 0][n] = v.x; Bs[skg * 4 + 1][n] = v.y;
            Bs[skg * 4 + 2][n] = v.z; Bs[skg * 4 + 3][n] = v.w;
        }
        __syncthreads();   // tile ready

        // two sequential 16-k phases; DO NOT fuse (VGPR cliff)
        #pragma unroll 1
        for (int ph = 0; ph < 2; ++ph) {
            const int kb = ph * 16;
            #pragma unroll
            for (int k = 0; k < 16; ++k) {
                float4 a0 = *(const float4*)&As[kb + k][ty * 4];
                float4 a1 = *(const float4*)&As[kb + k][64 + ty * 4];
                float4 b0 = *(const float4*)&Bs[kb + k][tx * 4];
#define FMAROW(I, AV)                                              \
                run[I][0] = __builtin_fmaf(AV, b0.x, run[I][0]);   \
                run[I][1] = __builtin_fmaf(AV, b0.y, run[I][1]);   \
                run[I][2] = __builtin_fmaf(AV, b0.z, run[I][2]);   \
                run[I][3] = __builtin_fmaf(AV, b0.w, run[I][3]);
                FMAROW(0, a0.x) FMAROW(1, a0.y) FMAROW(2, a0.z) FMAROW(3, a0.w)
                FMAROW(4, a1.x) FMAROW(5, a1.y) FMAROW(6, a1.z) FMAROW(7, a1.w)
#undef FMAROW
            }
        }

        // OpenBLAS panel boundary after k=384 (it=11) and k=768 (it=23)
        if (it == 11 || it == 23) {
            #pragma unroll
            for (int i = 0; i < 8; ++i)
                #pragma unroll
                for (int j = 0; j < 4; ++j) {
                    tot[i][j] = tot[i][j] + run[i][j];
                    run[i][j] = 0.f;
                }
        }
    }
    __syncthreads();

    // sign-pack: thread -> 8 nibbles (one per row, cols tx*4..+3)
    #pragma unroll
    for (int i = 0; i < 8; ++i) {
        const int r = (i < 4) ? (ty * 4 + i) : (64 + ty * 4 + (i - 4));
        unsigned char nb = 0;
        #pragma unroll
        for (int j = 0; j < 4; ++j) {
            float v = tot[i][j] + run[i][j];   // C = (P0+P1)+P2
            nb |= (unsigned char)((v > 0.0f) ? (1u << j) : 0u);
        }
        sb[r][tx] = nb;
    }
    __syncthreads();

    if (tid < BM) {
        const int r = tid;
        u64 row = 0ULL;
        #pragma unroll
        for (int nb2 = 0; nb2 < 16; ++nb2)
            row |= (u64)(sb[r][nb2] & 0xFu) << (nb2 * 4);
        const int m = m0 + r;
        const int b = m >> 12;
        const int t = m & (T_ - 1);
        if (n0 < 512) {
            u16* dst = (n0 < 256) ? qc : kc;
            const int hb = (n0 & 255) >> 4;
            #pragma unroll
            for (int g = 0; g < 4; ++g)
                dst[((size_t)(b * H_ + hb + g)) * T_ + t] = (u16)((row >> (g * 16)) & 0xFFFFULL);
        } else {
            const int h = (n0 - 512) >> 6;
            vc[((size_t)(b * H_ + h)) * T_ + t] = row;
        }
    }
}

// ---------------------------------------------------------------------------
// Fused resolve + expand (bit-identical to the R19 proven kernel).
// ---------------------------------------------------------------------------
__global__ __launch_bounds__(256) void resolve_expand_kernel(
    const u16* __restrict__ qc, const u16* __restrict__ kc,
    const u64* __restrict__ vc,
    const float* __restrict__ emb0, const float* __restrict__ emb1,
    float* __restrict__ out)
{
    __shared__ u16 keys[T_];
    __shared__ u16 pos[T_];
    __shared__ unsigned int cnt[256];
    __shared__ unsigned int offs[257];
    __shared__ float e_lo[64], e_hi[64];

    const int bh = blockIdx.x;
    const int b = bh >> 4, h = bh & 15;
    const u16* kck = kc + (size_t)bh * T_;
    const u16* qck = qc + (size_t)bh * T_;
    const u64* vck = vc + (size_t)bh * T_;
    const int tid = threadIdx.x;

    if (tid < 64) {
        e_lo[tid] = bf16r(emb0[h * 64 + tid]);
        e_hi[tid] = bf16r(emb1[h * 64 + tid]);
    }
    cnt[tid] = 0;
    __syncthreads();
    for (int t = tid; t < T_; t += 256) {
        u16 kv = kck[t];
        keys[t] = kv;
        atomicAdd(&cnt[kv & 255], 1u);
    }
    __syncthreads();
    if (tid == 0) {
        unsigned int s = 0;
        for (int i = 0; i < 256; ++i) { offs[i] = s; s += cnt[i]; }
        offs[256] = s;
    }
    __syncthreads();
    cnt[tid] = offs[tid];
    __syncthreads();
    for (int t = tid; t < T_; t += 256) {
        unsigned int p = atomicAdd(&cnt[keys[t] & 255], 1u);
        pos[p] = (u16)t;
    }
    __syncthreads();
    for (int t = tid; t < T_; t += 256) {
        u16 code = qck[t];
        const int bkt = code & 255;
        int best = -1;
        const unsigned int s = offs[bkt], e = offs[bkt + 1];
        for (unsigned int it = s; it < e; ++it) {
            int j = (int)pos[it];
            if (j < t && keys[j] == code && j > best) best = j;
        }
        u64 yv = (best >= 0) ? vck[best] : 0ULL;
        float* orow = out + ((size_t)(b * T_ + t)) * D_ + h * 64;
        #pragma unroll
        for (int e2 = 0; e2 < 64; ++e2)
            orow[e2] = ((yv >> e2) & 1ULL) ? e_hi[e2] : e_lo[e2];
    }
}

// ---------------------------------------------------------------------------
extern "C" void kernel_launch(void* const* d_in, const int* in_sizes, int n_in,
                              void* d_out, int out_size, void* d_ws, size_t ws_size,
                              hipStream_t stream)
{
    const float* x  = (const float*)d_in[0];
    const float* Wq = (const float*)d_in[1];
    const float* Wk = (const float*)d_in[2];
    const float* Wv = (const float*)d_in[3];
    const float* e0 = (const float*)d_in[4];
    const float* e1 = (const float*)d_in[5];

    char* ws = (char*)d_ws;
    // footprint 3 MB (safe): qc 512K | kc 512K | vc 2M
    u16* qc = (u16*)(ws + 0);
    u16* kc = (u16*)(ws + 524288);
    u64* vc = (u64*)(ws + 1048576);
    float* out = (float*)d_out;

    dim3 gA(NTOT / BN, M_ / BM);   // (24, 128), x-major shares x-rows in L2
    gemm_pack_kernel<<<gA, 256, 0, stream>>>(x, Wq, Wk, Wv, qc, kc, vc);
    resolve_expand_kernel<<<B_ * H_, 256, 0, stream>>>(qc, kc, vc, e0, e1, out);
}

// Round 27
// 748.176 us; speedup vs baseline: 12.2151x; 1.0354x over previous
//
#include <hip/hip_runtime.h>
#include <stdint.h>

#define B_   4
#define T_   4096
#define D_   1024
#define H_   16
#define M_   16384
#define NTOT 1536
#define BM   128
#define BN   64
#define BKK  16
#define KC   384   // OpenBLAS SGEMM_DEFAULT_Q (Haswell/Zen)

typedef unsigned short u16;
typedef unsigned long long u64;

__device__ __forceinline__ float bf16r(float f) {
    unsigned int u = __float_as_uint(f);
    u += 0x7FFFu + ((u >> 16) & 1u);
    return __uint_as_float(u & 0xFFFF0000u);
}

// ---------------------------------------------------------------------------
// GEMM on RAW f32 inputs, OpenBLAS order (serial FMA chain per element within
// KC=384 panels, C += per panel, (P0+P1)+P2). 128x64 block, 8x4 per thread
// (row quadrants), b128 LDS reads, 64 accumulator regs (VGPR 80, no spill).
// This is the proven R21 configuration -- the empirical optimum after six
// structural experiments (bigger tiles, prefetch, double-buffer, DMA, BKK=32)
// all regressed via the VGPR cliff or LDS-conflict growth.
// ---------------------------------------------------------------------------
__global__ __launch_bounds__(256) void gemm_pack_kernel(
    const float* __restrict__ x, const float* __restrict__ Wq,
    const float* __restrict__ Wk, const float* __restrict__ Wv,
    u16* __restrict__ qc, u16* __restrict__ kc, u64* __restrict__ vc)
{
    __shared__ float As[BKK][BM + 4];   // [16][132]
    __shared__ float Bs[BKK][BN + 4];   // [16][68]
    __shared__ unsigned char sb[BM][17];

    const int tid = threadIdx.x;
    const int tx = tid & 15;            // N: cols tx*4..+3
    const int ty = tid >> 4;            // M: rows ty*4+i and 64+ty*4+i
    const int n0 = blockIdx.x * BN;     // x-major: n-tiles share x rows in L2
    const int m0 = blockIdx.y * BM;

    const float* Wsrc; int f0;
    if (n0 < 256)      { Wsrc = Wq; f0 = n0; }
    else if (n0 < 512) { Wsrc = Wk; f0 = n0 - 256; }
    else               { Wsrc = Wv; f0 = n0 - 512; }

    float run[8][4], tot[8][4];
    #pragma unroll
    for (int i = 0; i < 8; ++i)
        #pragma unroll
        for (int j = 0; j < 4; ++j) { run[i][j] = 0.f; tot[i][j] = 0.f; }

    for (int k0 = 0; k0 < D_; k0 += BKK) {
        // stage x: 128 rows x 16 k = 512 float4 (2/thread)
        #pragma unroll
        for (int l = 0; l < 2; ++l) {
            const int idx = tid + l * 256;
            const int m  = idx >> 2;           // 0..127
            const int kg = idx & 3;            // float4 group in k
            float4 v4 = *(const float4*)&x[(size_t)(m0 + m) * D_ + k0 + kg * 4];
            As[kg * 4 + 0][m] = v4.x; As[kg * 4 + 1][m] = v4.y;
            As[kg * 4 + 2][m] = v4.z; As[kg * 4 + 3][m] = v4.w;
        }
        // stage W: 64 rows x 16 k = 256 float4 (1/thread)
        {
            const int n  = tid >> 2;           // 0..63
            const int kg = tid & 3;
            float4 v4 = *(const float4*)&Wsrc[(size_t)(f0 + n) * D_ + k0 + kg * 4];
            Bs[kg * 4 + 0][n] = v4.x; Bs[kg * 4 + 1][n] = v4.y;
            Bs[kg * 4 + 2][n] = v4.z; Bs[kg * 4 + 3][n] = v4.w;
        }
        __syncthreads();

        #pragma unroll
        for (int k = 0; k < BKK; ++k) {
            float4 a0 = *(const float4*)&As[k][ty * 4];
            float4 a1 = *(const float4*)&As[k][64 + ty * 4];
            float4 b0 = *(const float4*)&Bs[k][tx * 4];
#define FMAROW(I, AV)                                              \
            run[I][0] = __builtin_fmaf(AV, b0.x, run[I][0]);       \
            run[I][1] = __builtin_fmaf(AV, b0.y, run[I][1]);       \
            run[I][2] = __builtin_fmaf(AV, b0.z, run[I][2]);       \
            run[I][3] = __builtin_fmaf(AV, b0.w, run[I][3]);
            FMAROW(0, a0.x) FMAROW(1, a0.y) FMAROW(2, a0.z) FMAROW(3, a0.w)
            FMAROW(4, a1.x) FMAROW(5, a1.y) FMAROW(6, a1.z) FMAROW(7, a1.w)
#undef FMAROW
        }
        __syncthreads();

        const int kend = k0 + BKK;
        if (kend == KC || kend == 2 * KC) {    // OpenBLAS panel boundary
            #pragma unroll
            for (int i = 0; i < 8; ++i)
                #pragma unroll
                for (int j = 0; j < 4; ++j) {
                    tot[i][j] = tot[i][j] + run[i][j];
                    run[i][j] = 0.f;
                }
        }
    }

    // sign-pack: thread -> 8 nibbles (one per row, cols tx*4..+3)
    #pragma unroll
    for (int i = 0; i < 8; ++i) {
        const int r = (i < 4) ? (ty * 4 + i) : (64 + ty * 4 + (i - 4));
        unsigned char nb = 0;
        #pragma unroll
        for (int j = 0; j < 4; ++j) {
            float v = tot[i][j] + run[i][j];   // C = (P0+P1)+P2
            nb |= (unsigned char)((v > 0.0f) ? (1u << j) : 0u);
        }
        sb[r][tx] = nb;
    }
    __syncthreads();

    if (tid < BM) {
        const int r = tid;
        u64 row = 0ULL;
        #pragma unroll
        for (int nb = 0; nb < 16; ++nb)
            row |= (u64)(sb[r][nb] & 0xFu) << (nb * 4);
        const int m = m0 + r;
        const int b = m >> 12;
        const int t = m & (T_ - 1);
        if (n0 < 512) {
            u16* dst = (n0 < 256) ? qc : kc;
            const int hb = (n0 & 255) >> 4;    // 4 heads per 64-col tile
            #pragma unroll
            for (int g = 0; g < 4; ++g)
                dst[((size_t)(b * H_ + hb + g)) * T_ + t] = (u16)((row >> (g * 16)) & 0xFFFFULL);
        } else {
            const int h = (n0 - 512) >> 6;     // 1 head per 64-col tile
            vc[((size_t)(b * H_ + h)) * T_ + t] = row;
        }
    }
}

// ---------------------------------------------------------------------------
// Fused resolve + expand (bit-identical to the R19 proven kernel).
// ---------------------------------------------------------------------------
__global__ __launch_bounds__(256) void resolve_expand_kernel(
    const u16* __restrict__ qc, const u16* __restrict__ kc,
    const u64* __restrict__ vc,
    const float* __restrict__ emb0, const float* __restrict__ emb1,
    float* __restrict__ out)
{
    __shared__ u16 keys[T_];
    __shared__ u16 pos[T_];
    __shared__ unsigned int cnt[256];
    __shared__ unsigned int offs[257];
    __shared__ float e_lo[64], e_hi[64];

    const int bh = blockIdx.x;
    const int b = bh >> 4, h = bh & 15;
    const u16* kck = kc + (size_t)bh * T_;
    const u16* qck = qc + (size_t)bh * T_;
    const u64* vck = vc + (size_t)bh * T_;
    const int tid = threadIdx.x;

    if (tid < 64) {
        e_lo[tid] = bf16r(emb0[h * 64 + tid]);
        e_hi[tid] = bf16r(emb1[h * 64 + tid]);
    }
    cnt[tid] = 0;
    __syncthreads();
    for (int t = tid; t < T_; t += 256) {
        u16 kv = kck[t];
        keys[t] = kv;
        atomicAdd(&cnt[kv & 255], 1u);
    }
    __syncthreads();
    if (tid == 0) {
        unsigned int s = 0;
        for (int i = 0; i < 256; ++i) { offs[i] = s; s += cnt[i]; }
        offs[256] = s;
    }
    __syncthreads();
    cnt[tid] = offs[tid];
    __syncthreads();
    for (int t = tid; t < T_; t += 256) {
        unsigned int p = atomicAdd(&cnt[keys[t] & 255], 1u);
        pos[p] = (u16)t;
    }
    __syncthreads();
    for (int t = tid; t < T_; t += 256) {
        u16 code = qck[t];
        const int bkt = code & 255;
        int best = -1;
        const unsigned int s = offs[bkt], e = offs[bkt + 1];
        for (unsigned int it = s; it < e; ++it) {
            int j = (int)pos[it];
            if (j < t && keys[j] == code && j > best) best = j;
        }
        u64 yv = (best >= 0) ? vck[best] : 0ULL;
        float* orow = out + ((size_t)(b * T_ + t)) * D_ + h * 64;
        #pragma unroll
        for (int e2 = 0; e2 < 64; ++e2)
            orow[e2] = ((yv >> e2) & 1ULL) ? e_hi[e2] : e_lo[e2];
    }
}

// ---------------------------------------------------------------------------
extern "C" void kernel_launch(void* const* d_in, const int* in_sizes, int n_in,
                              void* d_out, int out_size, void* d_ws, size_t ws_size,
                              hipStream_t stream)
{
    const float* x  = (const float*)d_in[0];
    const float* Wq = (const float*)d_in[1];
    const float* Wk = (const float*)d_in[2];
    const float* Wv = (const float*)d_in[3];
    const float* e0 = (const float*)d_in[4];
    const float* e1 = (const float*)d_in[5];

    char* ws = (char*)d_ws;
    // footprint 3 MB (safe): qc 512K | kc 512K | vc 2M
    u16* qc = (u16*)(ws + 0);
    u16* kc = (u16*)(ws + 524288);
    u64* vc = (u64*)(ws + 1048576);
    float* out = (float*)d_out;

    dim3 gA(NTOT / BN, M_ / BM);   // (24, 128), x-major shares x-rows in L2
    gemm_pack_kernel<<<gA, 256, 0, stream>>>(x, Wq, Wk, Wv, qc, kc, vc);
    resolve_expand_kernel<<<B_ * H_, 256, 0, stream>>>(qc, kc, vc, e0, e1, out);
}